// Round 2
// baseline (93.075 us; speedup 1.0000x reference)
//
#include <hip/hip_runtime.h>
#include <math.h>

// Problem constants (D_IN == D_OUT == 4096)
constexpr int   D     = 4096;
constexpr float ALPHA = 0.001f;   // heb_lr
constexpr float GAMMA = 0.99f;
constexpr float EPSC  = 0.0001f;

// Chained-scan decomposition
constexpr int CHUNK  = 32;             // rows per chunk
constexpr int NCHUNK = D / CHUNK;      // 128
constexpr int TPB    = 256;
constexpr int CPB    = TPB * 4;        // 1024 cols per block (float4/thread)
constexpr int NCT    = D / CPB;        // 4 column tiles
constexpr int NBLK   = NCHUNK * NCT;   // 512 blocks, vid = c*NCT + t

// ---------------------------------------------------------------------------
// Kernel 1: u = W @ x + b   (one wave per row, float4 coalesced)
// ---------------------------------------------------------------------------
__global__ __launch_bounds__(256) void k_gemv(const float* __restrict__ W,
                                              const float* __restrict__ x,
                                              const float* __restrict__ b,
                                              float* __restrict__ u) {
    const int wave = threadIdx.x >> 6;        // 0..3
    const int lane = threadIdx.x & 63;
    const int row  = (blockIdx.x << 2) + wave;
    const float4* Wr = reinterpret_cast<const float4*>(W + (size_t)row * D);
    const float4* xv = reinterpret_cast<const float4*>(x);
    float acc = 0.f;
    #pragma unroll
    for (int it = 0; it < D / 256; ++it) {    // 16 iterations: 64 lanes x float4
        const float4 w  = Wr[lane + it * 64];
        const float4 xx = xv[lane + it * 64];
        acc += w.x * xx.x + w.y * xx.y + w.z * xx.z + w.w * xx.w;
    }
    #pragma unroll
    for (int off = 32; off; off >>= 1) acc += __shfl_down(acc, off, 64);
    if (lane == 0) u[row] = acc + b[row];
}

// ---------------------------------------------------------------------------
// Kernel 2 (single block): zero scan flags+ticket; m = max(relu(u));
// y = r^2/m^2; exp_avg update; avg = mean; gf_pos/gf_neg per row.
// ---------------------------------------------------------------------------
__global__ __launch_bounds__(1024) void k_stats(const float* __restrict__ u,
                                                const float* __restrict__ ea_in,
                                                float* __restrict__ y_out,
                                                float* __restrict__ ea_out,
                                                float* __restrict__ gfp,
                                                float* __restrict__ gfn,
                                                int* __restrict__ flags) {
    __shared__ float sred[16];
    const int tid = threadIdx.x;

    // Re-init scan state every call (graph replay does not re-poison ws).
    if (tid <= NBLK) flags[tid] = 0;   // flags[0..NBLK-1] + ticket at [NBLK]

    float r[4];
    float lmax = 0.f;
    #pragma unroll
    for (int i = 0; i < 4; ++i) {
        float v = u[tid + i * 1024];
        v = fmaxf(v, 0.f);
        r[i] = v;
        lmax = fmaxf(lmax, v);
    }
    #pragma unroll
    for (int off = 32; off; off >>= 1) lmax = fmaxf(lmax, __shfl_down(lmax, off, 64));
    if ((tid & 63) == 0) sred[tid >> 6] = lmax;
    __syncthreads();
    if (tid == 0) {
        float v = sred[0];
        #pragma unroll
        for (int i = 1; i < 16; ++i) v = fmaxf(v, sred[i]);
        sred[0] = v;
    }
    __syncthreads();
    const float m = sred[0];
    const float inv_m2 = 1.f / (m * m);

    float e[4];
    float lsum = 0.f;
    #pragma unroll
    for (int i = 0; i < 4; ++i) {
        const int idx = tid + i * 1024;
        const float yv = r[i] * r[i] * inv_m2;   // r^LAMB / m^LAMB, LAMB=2
        y_out[idx] = yv;
        const float ev = GAMMA * ea_in[idx] + (1.f - GAMMA) * yv;
        ea_out[idx] = ev;
        e[i] = ev;
        lsum += ev;
    }
    #pragma unroll
    for (int off = 32; off; off >>= 1) lsum += __shfl_down(lsum, off, 64);
    __syncthreads();                     // protect sred reuse (m reads done)
    if ((tid & 63) == 0) sred[tid >> 6] = lsum;
    __syncthreads();
    if (tid == 0) {
        float v = 0.f;
        #pragma unroll
        for (int i = 0; i < 16; ++i) v += sred[i];
        sred[0] = v;
    }
    __syncthreads();
    const float inv_avg = (float)D / sred[0];
    #pragma unroll
    for (int i = 0; i < 4; ++i) {
        const int idx = tid + i * 1024;
        const float a = e[i] * inv_avg;
        const float g = EPSC * tanhf(-EPSC * (a - 1.f)) + 1.f;
        gfp[idx] = g;
        gfn[idx] = 1.f / g;
    }
}

// ---------------------------------------------------------------------------
// Kernel 3: fused chunk-partial + decoupled-lookback scan + Hebbian update
// + sign-split decay. W chunk staged in registers; read once, write once.
//
// vid (ticket-ordered) -> (c = vid/NCT chunk, t = vid%NCT col tile).
// Ticket guarantees resident blocks hold the lowest vids -> predecessors of
// any spinning block are always scheduled -> no deadlock at any occupancy.
// Payload (column prefix vectors) uses agent-scope relaxed atomics
// (write-through to coherence point; no whole-L2 inv/wb in the spin path).
// ---------------------------------------------------------------------------
__global__ __launch_bounds__(256) void k_fused(
    const float* __restrict__ W, const float* __restrict__ x,
    const float* __restrict__ y, const float* __restrict__ gfp,
    const float* __restrict__ gfn, float* __restrict__ Pagg,
    float* __restrict__ Pinc, int* __restrict__ flags,
    float* __restrict__ W2)
{
    __shared__ int s_vid;
    __shared__ int s_st;
    const int tid = threadIdx.x;
    if (tid == 0) s_vid = atomicAdd(&flags[NBLK], 1);   // ticket
    __syncthreads();
    const int vid = s_vid;
    const int t   = vid & (NCT - 1);
    const int c   = vid >> 2;            // NCT == 4
    const int j   = t * CPB + tid * 4;
    const int k0  = c * CHUNK;

    // Phase 1: load chunk into registers, accumulate column partials.
    const float4* Wp = reinterpret_cast<const float4*>(W + (size_t)k0 * D + j);
    float4 wreg[CHUNK];                  // 128 VGPRs, statically indexed
    float4 acc = make_float4(0.f, 0.f, 0.f, 0.f);
    #pragma unroll
    for (int k = 0; k < CHUNK; ++k) {
        wreg[k] = Wp[(size_t)k * (D / 4)];
        const float yv = y[k0 + k];
        acc.x += yv * wreg[k].x; acc.y += yv * wreg[k].y;
        acc.z += yv * wreg[k].z; acc.w += yv * wreg[k].w;
    }

    // Publish aggregate, then look back for the exclusive prefix.
    float4 ex = make_float4(0.f, 0.f, 0.f, 0.f);
    if (c > 0) {
        float* pa = Pagg + (size_t)vid * CPB + tid * 4;
        __hip_atomic_store(pa + 0, acc.x, __ATOMIC_RELAXED, __HIP_MEMORY_SCOPE_AGENT);
        __hip_atomic_store(pa + 1, acc.y, __ATOMIC_RELAXED, __HIP_MEMORY_SCOPE_AGENT);
        __hip_atomic_store(pa + 2, acc.z, __ATOMIC_RELAXED, __HIP_MEMORY_SCOPE_AGENT);
        __hip_atomic_store(pa + 3, acc.w, __ATOMIC_RELAXED, __HIP_MEMORY_SCOPE_AGENT);
        __syncthreads();                 // drains vmcnt: all payload stores done
        if (tid == 0)
            __hip_atomic_store(&flags[vid], 1, __ATOMIC_RELEASE, __HIP_MEMORY_SCOPE_AGENT);

        int i = c - 1;
        for (;;) {
            if (tid == 0) {
                int st = __hip_atomic_load(&flags[i * NCT + t], __ATOMIC_RELAXED,
                                           __HIP_MEMORY_SCOPE_AGENT);
                while (st == 0) {
                    __builtin_amdgcn_s_sleep(1);
                    st = __hip_atomic_load(&flags[i * NCT + t], __ATOMIC_RELAXED,
                                           __HIP_MEMORY_SCOPE_AGENT);
                }
                s_st = st;
            }
            __syncthreads();
            const int st = s_st;
            const float* ps = (st == 2 ? Pinc : Pagg)
                              + (size_t)(i * NCT + t) * CPB + tid * 4;
            ex.x += __hip_atomic_load(ps + 0, __ATOMIC_RELAXED, __HIP_MEMORY_SCOPE_AGENT);
            ex.y += __hip_atomic_load(ps + 1, __ATOMIC_RELAXED, __HIP_MEMORY_SCOPE_AGENT);
            ex.z += __hip_atomic_load(ps + 2, __ATOMIC_RELAXED, __HIP_MEMORY_SCOPE_AGENT);
            ex.w += __hip_atomic_load(ps + 3, __ATOMIC_RELAXED, __HIP_MEMORY_SCOPE_AGENT);
            if (st == 2) break;          // hit an inclusive prefix: done
            --i;
            __syncthreads();             // separate s_st read from next write
        }
    }

    // Publish inclusive prefix (skip for the last chunk: no successors).
    if (c < NCHUNK - 1) {
        float* pi = Pinc + (size_t)vid * CPB + tid * 4;
        __hip_atomic_store(pi + 0, ex.x + acc.x, __ATOMIC_RELAXED, __HIP_MEMORY_SCOPE_AGENT);
        __hip_atomic_store(pi + 1, ex.y + acc.y, __ATOMIC_RELAXED, __HIP_MEMORY_SCOPE_AGENT);
        __hip_atomic_store(pi + 2, ex.z + acc.z, __ATOMIC_RELAXED, __HIP_MEMORY_SCOPE_AGENT);
        __hip_atomic_store(pi + 3, ex.w + acc.w, __ATOMIC_RELAXED, __HIP_MEMORY_SCOPE_AGENT);
        __syncthreads();
        if (tid == 0)
            __hip_atomic_store(&flags[vid], 2, __ATOMIC_RELEASE, __HIP_MEMORY_SCOPE_AGENT);
    }

    // Phase 2: resume inclusive scan from registers; fuse delta + decay.
    const float4 xv = *reinterpret_cast<const float4*>(x + j);
    float4 s = ex;
    float4* W2p = reinterpret_cast<float4*>(W2 + (size_t)k0 * D + j);
    #pragma unroll
    for (int k = 0; k < CHUNK; ++k) {
        const int row = k0 + k;
        const float yv = y[row];
        const float gp = gfp[row];
        const float gn = gfn[row];
        const float4 w = wreg[k];
        s.x += yv * w.x; s.y += yv * w.y;
        s.z += yv * w.z; s.w += yv * w.w;
        float4 o;
        {
            const float w1 = w.x + ALPHA * (yv * xv.x - yv * s.x);
            o.x = w1 > 0.f ? w1 * gp : (w1 < 0.f ? w1 * gn : 0.f);
        }
        {
            const float w1 = w.y + ALPHA * (yv * xv.y - yv * s.y);
            o.y = w1 > 0.f ? w1 * gp : (w1 < 0.f ? w1 * gn : 0.f);
        }
        {
            const float w1 = w.z + ALPHA * (yv * xv.z - yv * s.z);
            o.z = w1 > 0.f ? w1 * gp : (w1 < 0.f ? w1 * gn : 0.f);
        }
        {
            const float w1 = w.w + ALPHA * (yv * xv.w - yv * s.w);
            o.w = w1 > 0.f ? w1 * gp : (w1 < 0.f ? w1 * gn : 0.f);
        }
        W2p[(size_t)k * (D / 4)] = o;
    }
}

// ---------------------------------------------------------------------------
extern "C" void kernel_launch(void* const* d_in, const int* in_sizes, int n_in,
                              void* d_out, int out_size, void* d_ws, size_t ws_size,
                              hipStream_t stream) {
    const float* x  = (const float*)d_in[0];
    const float* W  = (const float*)d_in[1];
    const float* b  = (const float*)d_in[2];
    const float* ea = (const float*)d_in[3];

    float* out    = (float*)d_out;
    float* y_out  = out;                        // [D]
    float* W2_out = out + D;                    // [D*D]
    float* ea_out = out + D + (size_t)D * D;    // [D]

    float* ws    = (float*)d_ws;
    float* u     = ws;                          // [D]
    float* gfp   = ws + D;                      // [D]
    float* gfn   = ws + 2 * D;                  // [D]
    float* Pagg  = ws + 3 * D;                  // [NBLK*CPB] = 2 MB
    float* Pinc  = Pagg + (size_t)NBLK * CPB;   // [NBLK*CPB] = 2 MB
    int*   flags = (int*)(Pinc + (size_t)NBLK * CPB); // [NBLK+1] (+ticket)

    k_gemv<<<D / 4, 256, 0, stream>>>(W, x, b, u);
    k_stats<<<1, 1024, 0, stream>>>(u, ea, y_out, ea_out, gfp, gfn, flags);
    k_fused<<<NBLK, TPB, 0, stream>>>(W, x, y_out, gfp, gfn, Pagg, Pinc, flags, W2_out);
}

// Round 3
// 55.125 us; speedup vs baseline: 1.6884x; 1.6884x over previous
//
#include <hip/hip_runtime.h>
#include <math.h>

// Problem constants (D_IN == D_OUT == 4096)
constexpr int   D     = 4096;
constexpr float ALPHA = 0.001f;   // heb_lr
constexpr float GAMMA = 0.99f;
constexpr float EPSC  = 0.0001f;

// Scan decomposition
constexpr int CHUNK  = 32;             // rows per chunk
constexpr int NCHUNK = D / CHUNK;      // 128
constexpr int TPB    = 256;
constexpr int CPB    = TPB * 4;        // 1024 cols per block (float4/thread)
constexpr int NCT    = D / CPB;        // 4 column tiles

// ---------------------------------------------------------------------------
// Kernel 1: u = W @ x + b   (one wave per row, float4 coalesced)
// ---------------------------------------------------------------------------
__global__ __launch_bounds__(256) void k_gemv(const float* __restrict__ W,
                                              const float* __restrict__ x,
                                              const float* __restrict__ b,
                                              float* __restrict__ u) {
    const int wave = threadIdx.x >> 6;        // 0..3
    const int lane = threadIdx.x & 63;
    const int row  = (blockIdx.x << 2) + wave;
    const float4* Wr = reinterpret_cast<const float4*>(W + (size_t)row * D);
    const float4* xv = reinterpret_cast<const float4*>(x);
    float acc = 0.f;
    #pragma unroll
    for (int it = 0; it < D / 256; ++it) {    // 16 iterations: 64 lanes x float4
        const float4 w  = Wr[lane + it * 64];
        const float4 xx = xv[lane + it * 64];
        acc += w.x * xx.x + w.y * xx.y + w.z * xx.z + w.w * xx.w;
    }
    #pragma unroll
    for (int off = 32; off; off >>= 1) acc += __shfl_down(acc, off, 64);
    if (lane == 0) u[row] = acc + b[row];
}

// ---------------------------------------------------------------------------
// Kernel 2 (single block): m = max(relu(u)); y = r^2/m^2; exp_avg update;
// avg = mean(exp_avg_new); gf_pos/gf_neg per row.
// ---------------------------------------------------------------------------
__global__ __launch_bounds__(1024) void k_stats(const float* __restrict__ u,
                                                const float* __restrict__ ea_in,
                                                float* __restrict__ y_out,
                                                float* __restrict__ ea_out,
                                                float* __restrict__ gfp,
                                                float* __restrict__ gfn) {
    __shared__ float sred[16];
    const int tid = threadIdx.x;

    float r[4];
    float lmax = 0.f;
    #pragma unroll
    for (int i = 0; i < 4; ++i) {
        float v = u[tid + i * 1024];
        v = fmaxf(v, 0.f);
        r[i] = v;
        lmax = fmaxf(lmax, v);
    }
    #pragma unroll
    for (int off = 32; off; off >>= 1) lmax = fmaxf(lmax, __shfl_down(lmax, off, 64));
    if ((tid & 63) == 0) sred[tid >> 6] = lmax;
    __syncthreads();
    if (tid == 0) {
        float v = sred[0];
        #pragma unroll
        for (int i = 1; i < 16; ++i) v = fmaxf(v, sred[i]);
        sred[0] = v;
    }
    __syncthreads();
    const float m = sred[0];
    const float inv_m2 = 1.f / (m * m);

    float e[4];
    float lsum = 0.f;
    #pragma unroll
    for (int i = 0; i < 4; ++i) {
        const int idx = tid + i * 1024;
        const float yv = r[i] * r[i] * inv_m2;   // r^LAMB / m^LAMB, LAMB=2
        y_out[idx] = yv;
        const float ev = GAMMA * ea_in[idx] + (1.f - GAMMA) * yv;
        ea_out[idx] = ev;
        e[i] = ev;
        lsum += ev;
    }
    #pragma unroll
    for (int off = 32; off; off >>= 1) lsum += __shfl_down(lsum, off, 64);
    __syncthreads();                     // protect sred reuse (m reads done)
    if ((tid & 63) == 0) sred[tid >> 6] = lsum;
    __syncthreads();
    if (tid == 0) {
        float v = 0.f;
        #pragma unroll
        for (int i = 0; i < 16; ++i) v += sred[i];
        sred[0] = v;
    }
    __syncthreads();
    const float inv_avg = (float)D / sred[0];
    #pragma unroll
    for (int i = 0; i < 4; ++i) {
        const int idx = tid + i * 1024;
        const float a = e[i] * inv_avg;
        const float g = EPSC * tanhf(-EPSC * (a - 1.f)) + 1.f;
        gfp[idx] = g;
        gfn[idx] = 1.f / g;
    }
}

// ---------------------------------------------------------------------------
// Kernel 3: per-chunk column partial sums  P[c,j] = sum_{k in chunk c} y[k]*W[k,j]
// ---------------------------------------------------------------------------
__global__ __launch_bounds__(256) void k_partial(const float* __restrict__ W,
                                                 const float* __restrict__ y,
                                                 float* __restrict__ P) {
    const int j  = blockIdx.x * CPB + threadIdx.x * 4;
    const int c  = blockIdx.y;
    const int k0 = c * CHUNK;
    const float4* Wp = reinterpret_cast<const float4*>(W + (size_t)k0 * D + j);
    float4 acc = make_float4(0.f, 0.f, 0.f, 0.f);
    #pragma unroll 8
    for (int k = 0; k < CHUNK; ++k) {
        const float yv = y[k0 + k];
        const float4 w = Wp[(size_t)k * (D / 4)];
        acc.x += yv * w.x; acc.y += yv * w.y;
        acc.z += yv * w.z; acc.w += yv * w.w;
    }
    *reinterpret_cast<float4*>(P + (size_t)c * D + j) = acc;
}

// ---------------------------------------------------------------------------
// Kernel 4: exclusive prefix over preceding chunk partials (independent,
// coalesced, L2/L3-resident loads — no serial chain), then resume inclusive
// scan within chunk; fuse Hebbian delta + sign-split decay.
//   S[l,j] = sum_{i<c} P[i,j] + sum_{k0<=k<=l} y[k] W[k,j]
//   w1 = W + ALPHA*(y[l]*x[j] - y[l]*S[l,j])
//   w2 = w1>0 ? w1*gf_pos[l] : (w1<0 ? w1*gf_neg[l] : 0)
// ---------------------------------------------------------------------------
__global__ __launch_bounds__(256) void k_update(const float* __restrict__ W,
                                                const float* __restrict__ x,
                                                const float* __restrict__ y,
                                                const float* __restrict__ P,
                                                const float* __restrict__ gfp,
                                                const float* __restrict__ gfn,
                                                float* __restrict__ W2) {
    const int j  = blockIdx.x * CPB + threadIdx.x * 4;
    const int c  = blockIdx.y;
    const int k0 = c * CHUNK;

    // Exclusive prefix: sum of preceding chunk partials (two independent
    // accumulator chains; loads are independent -> compiler pipelines).
    const float4* Pp = reinterpret_cast<const float4*>(P + j);
    float4 a0 = make_float4(0.f, 0.f, 0.f, 0.f);
    float4 a1 = make_float4(0.f, 0.f, 0.f, 0.f);
    int i = 0;
    #pragma unroll 4
    for (; i + 2 <= c; i += 2) {
        const float4 p0 = Pp[(size_t)i * (D / 4)];
        const float4 p1 = Pp[(size_t)(i + 1) * (D / 4)];
        a0.x += p0.x; a0.y += p0.y; a0.z += p0.z; a0.w += p0.w;
        a1.x += p1.x; a1.y += p1.y; a1.z += p1.z; a1.w += p1.w;
    }
    if (i < c) {
        const float4 p0 = Pp[(size_t)i * (D / 4)];
        a0.x += p0.x; a0.y += p0.y; a0.z += p0.z; a0.w += p0.w;
    }
    float4 s;
    s.x = a0.x + a1.x; s.y = a0.y + a1.y;
    s.z = a0.z + a1.z; s.w = a0.w + a1.w;

    const float4 xv = *reinterpret_cast<const float4*>(x + j);
    const float4* Wp  = reinterpret_cast<const float4*>(W + (size_t)k0 * D + j);
    float4*       W2p = reinterpret_cast<float4*>(W2 + (size_t)k0 * D + j);
    #pragma unroll 4
    for (int k = 0; k < CHUNK; ++k) {
        const int row = k0 + k;
        const float yv = y[row];
        const float gp = gfp[row];
        const float gn = gfn[row];
        const float4 w = Wp[(size_t)k * (D / 4)];
        s.x += yv * w.x; s.y += yv * w.y;
        s.z += yv * w.z; s.w += yv * w.w;
        float4 o;
        {
            const float w1 = w.x + ALPHA * (yv * xv.x - yv * s.x);
            o.x = w1 > 0.f ? w1 * gp : (w1 < 0.f ? w1 * gn : 0.f);
        }
        {
            const float w1 = w.y + ALPHA * (yv * xv.y - yv * s.y);
            o.y = w1 > 0.f ? w1 * gp : (w1 < 0.f ? w1 * gn : 0.f);
        }
        {
            const float w1 = w.z + ALPHA * (yv * xv.z - yv * s.z);
            o.z = w1 > 0.f ? w1 * gp : (w1 < 0.f ? w1 * gn : 0.f);
        }
        {
            const float w1 = w.w + ALPHA * (yv * xv.w - yv * s.w);
            o.w = w1 > 0.f ? w1 * gp : (w1 < 0.f ? w1 * gn : 0.f);
        }
        W2p[(size_t)k * (D / 4)] = o;
    }
}

// ---------------------------------------------------------------------------
extern "C" void kernel_launch(void* const* d_in, const int* in_sizes, int n_in,
                              void* d_out, int out_size, void* d_ws, size_t ws_size,
                              hipStream_t stream) {
    const float* x  = (const float*)d_in[0];
    const float* W  = (const float*)d_in[1];
    const float* b  = (const float*)d_in[2];
    const float* ea = (const float*)d_in[3];

    float* out    = (float*)d_out;
    float* y_out  = out;                        // [D]
    float* W2_out = out + D;                    // [D*D]
    float* ea_out = out + D + (size_t)D * D;    // [D]

    float* ws  = (float*)d_ws;
    float* u   = ws;                            // [D]
    float* gfp = ws + D;                        // [D]
    float* gfn = ws + 2 * D;                    // [D]
    float* P   = ws + 3 * D;                    // [NCHUNK * D] = 2 MB

    k_gemv<<<D / 4, 256, 0, stream>>>(W, x, b, u);
    k_stats<<<1, 1024, 0, stream>>>(u, ea, y_out, ea_out, gfp, gfn);
    dim3 grid(NCT, NCHUNK);
    k_partial<<<grid, TPB, 0, stream>>>(W, y_out, P);
    k_update<<<grid, TPB, 0, stream>>>(W, x, y_out, P, gfp, gfn, W2_out);
}

// Round 4
// 55.025 us; speedup vs baseline: 1.6915x; 1.0018x over previous
//
#include <hip/hip_runtime.h>
#include <hip/hip_cooperative_groups.h>
#include <math.h>

namespace cg = cooperative_groups;

// Problem constants (D_IN == D_OUT == 4096)
constexpr int   D     = 4096;
constexpr float ALPHA = 0.001f;   // heb_lr
constexpr float GAMMA = 0.99f;
constexpr float EPSC  = 0.0001f;

// Decomposition
constexpr int CHUNK  = 32;             // rows per chunk
constexpr int NCHUNK = D / CHUNK;      // 128
constexpr int TPB    = 256;
constexpr int CPB    = TPB * 4;        // 1024 cols per block (float4/thread)
constexpr int NCT    = D / CPB;        // 4 column tiles
constexpr int NBLK   = NCHUNK * NCT;   // 512 blocks

// ===========================================================================
// Fused cooperative kernel: W is read from global exactly once (into wreg),
// W2 written once. Grid syncs separate the three cross-block dependencies
// (u <- all W rows; P prefix <- all preceding chunks).
// ===========================================================================
__global__ __launch_bounds__(TPB, 2) void k_all(
    const float* __restrict__ W, const float* __restrict__ x,
    const float* __restrict__ b, const float* __restrict__ ea,
    float* __restrict__ y_out, float* __restrict__ W2,
    float* __restrict__ ea_out, float* __restrict__ u_part,
    float* __restrict__ P)
{
    cg::grid_group grid = cg::this_grid();
    const int tid  = threadIdx.x;
    const int bid  = blockIdx.x;
    const int c    = bid >> 2;           // chunk index (NCT == 4)
    const int t    = bid & 3;            // column tile
    const int j    = t * CPB + tid * 4;
    const int k0   = c * CHUNK;
    const int wv   = tid >> 6;
    const int lane = tid & 63;

    __shared__ float swred[4][CHUNK];
    __shared__ float sred[4];
    __shared__ float sm[2];              // m, sum(ea_new)
    __shared__ float sy[CHUNK], sgp[CHUNK], sgn[CHUNK];

    // ---- Phase A: stage W tile in registers; per-tile GEMV partials ----
    const float4  xv = *reinterpret_cast<const float4*>(x + j);
    const float4* Wp = reinterpret_cast<const float4*>(W + (size_t)k0 * D + j);
    float4 wreg[CHUNK];                  // 128 VGPRs, statically indexed
    #pragma unroll
    for (int k = 0; k < CHUNK; ++k) wreg[k] = Wp[(size_t)k * (D / 4)];

    #pragma unroll
    for (int k = 0; k < CHUNK; ++k) {
        float v = wreg[k].x * xv.x + wreg[k].y * xv.y
                + wreg[k].z * xv.z + wreg[k].w * xv.w;
        #pragma unroll
        for (int off = 32; off; off >>= 1) v += __shfl_down(v, off, 64);
        if (lane == 0) swred[wv][k] = v;
    }
    __syncthreads();
    if (tid < CHUNK)
        u_part[t * D + k0 + tid] =
            (swred[0][tid] + swred[1][tid]) + (swred[2][tid] + swred[3][tid]);

    grid.sync();

    // ---- Phase B: stats, computed redundantly but bitwise-identically ----
    // pass 1: m = max(relu(u))
    float lmax = 0.f;
    #pragma unroll
    for (int i = 0; i < D / TPB; ++i) {
        const int r = i * TPB + tid;
        const float uv = ((u_part[r] + u_part[D + r])
                        + (u_part[2 * D + r] + u_part[3 * D + r])) + b[r];
        lmax = fmaxf(lmax, uv);          // relu folded into max-with-0 init
    }
    #pragma unroll
    for (int off = 32; off; off >>= 1) lmax = fmaxf(lmax, __shfl_down(lmax, off, 64));
    if (lane == 0) sred[wv] = lmax;
    __syncthreads();
    if (tid == 0) sm[0] = fmaxf(fmaxf(sred[0], sred[1]), fmaxf(sred[2], sred[3]));
    __syncthreads();
    const float m      = sm[0];
    const float inv_m2 = 1.f / (m * m);

    // pass 2: sum(ea_new) for avg; block 0 writes y / ea outputs
    float lsum = 0.f;
    #pragma unroll
    for (int i = 0; i < D / TPB; ++i) {
        const int r = i * TPB + tid;
        const float uv = ((u_part[r] + u_part[D + r])
                        + (u_part[2 * D + r] + u_part[3 * D + r])) + b[r];
        const float rr = fmaxf(uv, 0.f);
        const float yv = rr * rr * inv_m2;            // r^2 / m^2 (LAMB=2)
        const float ev = GAMMA * ea[r] + (1.f - GAMMA) * yv;
        lsum += ev;
        if (bid == 0) { y_out[r] = yv; ea_out[r] = ev; }
    }
    #pragma unroll
    for (int off = 32; off; off >>= 1) lsum += __shfl_down(lsum, off, 64);
    __syncthreads();                      // sred reuse
    if (lane == 0) sred[wv] = lsum;
    __syncthreads();
    if (tid == 0) sm[1] = (sred[0] + sred[1]) + (sred[2] + sred[3]);
    __syncthreads();
    const float inv_avg = (float)D / sm[1];

    // pass 3: own-chunk y / gf factors into LDS (32 designated threads)
    const int toff = (c & 7) * CHUNK;     // chunk rows live at tids toff..toff+31
    if (tid >= toff && tid < toff + CHUNK) {
        const int k = tid - toff;
        const int r = (c >> 3) * TPB + tid;           // == k0 + k
        const float uv = ((u_part[r] + u_part[D + r])
                        + (u_part[2 * D + r] + u_part[3 * D + r])) + b[r];
        const float rr = fmaxf(uv, 0.f);
        const float yv = rr * rr * inv_m2;
        const float ev = GAMMA * ea[r] + (1.f - GAMMA) * yv;
        const float a  = ev * inv_avg;
        const float g  = EPSC * tanhf(-EPSC * (a - 1.f)) + 1.f;
        sy[k] = yv; sgp[k] = g; sgn[k] = 1.f / g;
    }
    __syncthreads();

    // ---- Phase C: chunk column partials P[c,j] from registers ----
    float4 acc = make_float4(0.f, 0.f, 0.f, 0.f);
    #pragma unroll
    for (int k = 0; k < CHUNK; ++k) {
        const float yv = sy[k];
        acc.x += yv * wreg[k].x; acc.y += yv * wreg[k].y;
        acc.z += yv * wreg[k].z; acc.w += yv * wreg[k].w;
    }
    *reinterpret_cast<float4*>(P + (size_t)c * D + j) = acc;

    grid.sync();

    // ---- Phase D: exclusive prefix over preceding chunks, then update ----
    const float4* Pp = reinterpret_cast<const float4*>(P + j);
    float4 a0 = make_float4(0.f, 0.f, 0.f, 0.f);
    float4 a1 = make_float4(0.f, 0.f, 0.f, 0.f);
    int i = 0;
    #pragma unroll 4
    for (; i + 2 <= c; i += 2) {
        const float4 p0 = Pp[(size_t)i * (D / 4)];
        const float4 p1 = Pp[(size_t)(i + 1) * (D / 4)];
        a0.x += p0.x; a0.y += p0.y; a0.z += p0.z; a0.w += p0.w;
        a1.x += p1.x; a1.y += p1.y; a1.z += p1.z; a1.w += p1.w;
    }
    if (i < c) {
        const float4 p0 = Pp[(size_t)i * (D / 4)];
        a0.x += p0.x; a0.y += p0.y; a0.z += p0.z; a0.w += p0.w;
    }
    float4 s;
    s.x = a0.x + a1.x; s.y = a0.y + a1.y;
    s.z = a0.z + a1.z; s.w = a0.w + a1.w;

    float4* W2p = reinterpret_cast<float4*>(W2 + (size_t)k0 * D + j);
    #pragma unroll
    for (int k = 0; k < CHUNK; ++k) {
        const float yv = sy[k];
        const float gp = sgp[k];
        const float gn = sgn[k];
        const float4 w = wreg[k];
        s.x += yv * w.x; s.y += yv * w.y;
        s.z += yv * w.z; s.w += yv * w.w;
        float4 o;
        {
            const float w1 = w.x + ALPHA * (yv * xv.x - yv * s.x);
            o.x = w1 > 0.f ? w1 * gp : (w1 < 0.f ? w1 * gn : 0.f);
        }
        {
            const float w1 = w.y + ALPHA * (yv * xv.y - yv * s.y);
            o.y = w1 > 0.f ? w1 * gp : (w1 < 0.f ? w1 * gn : 0.f);
        }
        {
            const float w1 = w.z + ALPHA * (yv * xv.z - yv * s.z);
            o.z = w1 > 0.f ? w1 * gp : (w1 < 0.f ? w1 * gn : 0.f);
        }
        {
            const float w1 = w.w + ALPHA * (yv * xv.w - yv * s.w);
            o.w = w1 > 0.f ? w1 * gp : (w1 < 0.f ? w1 * gn : 0.f);
        }
        W2p[(size_t)k * (D / 4)] = o;
    }
}

// ===========================================================================
// Fallback path (round-3 structure) if cooperative residency isn't met.
// ===========================================================================
__global__ __launch_bounds__(256) void k_gemv(const float* __restrict__ W,
                                              const float* __restrict__ x,
                                              const float* __restrict__ b,
                                              float* __restrict__ u) {
    const int wave = threadIdx.x >> 6;
    const int lane = threadIdx.x & 63;
    const int row  = (blockIdx.x << 2) + wave;
    const float4* Wr = reinterpret_cast<const float4*>(W + (size_t)row * D);
    const float4* xv = reinterpret_cast<const float4*>(x);
    float acc = 0.f;
    #pragma unroll
    for (int it = 0; it < D / 256; ++it) {
        const float4 w  = Wr[lane + it * 64];
        const float4 xx = xv[lane + it * 64];
        acc += w.x * xx.x + w.y * xx.y + w.z * xx.z + w.w * xx.w;
    }
    #pragma unroll
    for (int off = 32; off; off >>= 1) acc += __shfl_down(acc, off, 64);
    if (lane == 0) u[row] = acc + b[row];
}

__global__ __launch_bounds__(1024) void k_stats(const float* __restrict__ u,
                                                const float* __restrict__ ea_in,
                                                float* __restrict__ y_out,
                                                float* __restrict__ ea_out,
                                                float* __restrict__ gfp,
                                                float* __restrict__ gfn) {
    __shared__ float sred[16];
    const int tid = threadIdx.x;
    float r[4];
    float lmax = 0.f;
    #pragma unroll
    for (int i = 0; i < 4; ++i) {
        float v = u[tid + i * 1024];
        v = fmaxf(v, 0.f);
        r[i] = v;
        lmax = fmaxf(lmax, v);
    }
    #pragma unroll
    for (int off = 32; off; off >>= 1) lmax = fmaxf(lmax, __shfl_down(lmax, off, 64));
    if ((tid & 63) == 0) sred[tid >> 6] = lmax;
    __syncthreads();
    if (tid == 0) {
        float v = sred[0];
        #pragma unroll
        for (int i = 1; i < 16; ++i) v = fmaxf(v, sred[i]);
        sred[0] = v;
    }
    __syncthreads();
    const float m = sred[0];
    const float inv_m2 = 1.f / (m * m);
    float e[4];
    float lsum = 0.f;
    #pragma unroll
    for (int i = 0; i < 4; ++i) {
        const int idx = tid + i * 1024;
        const float yv = r[i] * r[i] * inv_m2;
        y_out[idx] = yv;
        const float ev = GAMMA * ea_in[idx] + (1.f - GAMMA) * yv;
        ea_out[idx] = ev;
        e[i] = ev;
        lsum += ev;
    }
    #pragma unroll
    for (int off = 32; off; off >>= 1) lsum += __shfl_down(lsum, off, 64);
    __syncthreads();
    if ((tid & 63) == 0) sred[tid >> 6] = lsum;
    __syncthreads();
    if (tid == 0) {
        float v = 0.f;
        #pragma unroll
        for (int i = 0; i < 16; ++i) v += sred[i];
        sred[0] = v;
    }
    __syncthreads();
    const float inv_avg = (float)D / sred[0];
    #pragma unroll
    for (int i = 0; i < 4; ++i) {
        const int idx = tid + i * 1024;
        const float a = e[i] * inv_avg;
        const float g = EPSC * tanhf(-EPSC * (a - 1.f)) + 1.f;
        gfp[idx] = g;
        gfn[idx] = 1.f / g;
    }
}

__global__ __launch_bounds__(256) void k_partial(const float* __restrict__ W,
                                                 const float* __restrict__ y,
                                                 float* __restrict__ P) {
    const int j  = blockIdx.x * CPB + threadIdx.x * 4;
    const int c  = blockIdx.y;
    const int k0 = c * CHUNK;
    const float4* Wp = reinterpret_cast<const float4*>(W + (size_t)k0 * D + j);
    float4 acc = make_float4(0.f, 0.f, 0.f, 0.f);
    #pragma unroll 8
    for (int k = 0; k < CHUNK; ++k) {
        const float yv = y[k0 + k];
        const float4 w = Wp[(size_t)k * (D / 4)];
        acc.x += yv * w.x; acc.y += yv * w.y;
        acc.z += yv * w.z; acc.w += yv * w.w;
    }
    *reinterpret_cast<float4*>(P + (size_t)c * D + j) = acc;
}

__global__ __launch_bounds__(256) void k_update(const float* __restrict__ W,
                                                const float* __restrict__ x,
                                                const float* __restrict__ y,
                                                const float* __restrict__ P,
                                                const float* __restrict__ gfp,
                                                const float* __restrict__ gfn,
                                                float* __restrict__ W2) {
    const int j  = blockIdx.x * CPB + threadIdx.x * 4;
    const int c  = blockIdx.y;
    const int k0 = c * CHUNK;
    const float4* Pp = reinterpret_cast<const float4*>(P + j);
    float4 a0 = make_float4(0.f, 0.f, 0.f, 0.f);
    float4 a1 = make_float4(0.f, 0.f, 0.f, 0.f);
    int i = 0;
    #pragma unroll 4
    for (; i + 2 <= c; i += 2) {
        const float4 p0 = Pp[(size_t)i * (D / 4)];
        const float4 p1 = Pp[(size_t)(i + 1) * (D / 4)];
        a0.x += p0.x; a0.y += p0.y; a0.z += p0.z; a0.w += p0.w;
        a1.x += p1.x; a1.y += p1.y; a1.z += p1.z; a1.w += p1.w;
    }
    if (i < c) {
        const float4 p0 = Pp[(size_t)i * (D / 4)];
        a0.x += p0.x; a0.y += p0.y; a0.z += p0.z; a0.w += p0.w;
    }
    float4 s;
    s.x = a0.x + a1.x; s.y = a0.y + a1.y;
    s.z = a0.z + a1.z; s.w = a0.w + a1.w;
    const float4 xv = *reinterpret_cast<const float4*>(x + j);
    const float4* Wp  = reinterpret_cast<const float4*>(W + (size_t)k0 * D + j);
    float4*       W2p = reinterpret_cast<float4*>(W2 + (size_t)k0 * D + j);
    #pragma unroll 4
    for (int k = 0; k < CHUNK; ++k) {
        const int row = k0 + k;
        const float yv = y[row];
        const float gp = gfp[row];
        const float gn = gfn[row];
        const float4 w = Wp[(size_t)k * (D / 4)];
        s.x += yv * w.x; s.y += yv * w.y;
        s.z += yv * w.z; s.w += yv * w.w;
        float4 o;
        {
            const float w1 = w.x + ALPHA * (yv * xv.x - yv * s.x);
            o.x = w1 > 0.f ? w1 * gp : (w1 < 0.f ? w1 * gn : 0.f);
        }
        {
            const float w1 = w.y + ALPHA * (yv * xv.y - yv * s.y);
            o.y = w1 > 0.f ? w1 * gp : (w1 < 0.f ? w1 * gn : 0.f);
        }
        {
            const float w1 = w.z + ALPHA * (yv * xv.z - yv * s.z);
            o.z = w1 > 0.f ? w1 * gp : (w1 < 0.f ? w1 * gn : 0.f);
        }
        {
            const float w1 = w.w + ALPHA * (yv * xv.w - yv * s.w);
            o.w = w1 > 0.f ? w1 * gp : (w1 < 0.f ? w1 * gn : 0.f);
        }
        W2p[(size_t)k * (D / 4)] = o;
    }
}

// ===========================================================================
extern "C" void kernel_launch(void* const* d_in, const int* in_sizes, int n_in,
                              void* d_out, int out_size, void* d_ws, size_t ws_size,
                              hipStream_t stream) {
    const float* x  = (const float*)d_in[0];
    const float* W  = (const float*)d_in[1];
    const float* b  = (const float*)d_in[2];
    const float* ea = (const float*)d_in[3];

    float* out    = (float*)d_out;
    float* y_out  = out;                        // [D]
    float* W2_out = out + D;                    // [D*D]
    float* ea_out = out + D + (size_t)D * D;    // [D]

    float* ws     = (float*)d_ws;
    float* u_part = ws;                         // [NCT * D] = 64 KB
    float* P      = ws + NCT * D;               // [NCHUNK * D] = 2 MB

    // Host-side residency check (pure query — graph-capture safe, result is
    // compile-time-deterministic): need 2 blocks/CU for the 512-block coop grid.
    static int coop_ok = -1;
    if (coop_ok < 0) {
        int nblk_per_cu = 0;
        hipError_t e = hipOccupancyMaxActiveBlocksPerMultiprocessor(
            &nblk_per_cu, (const void*)k_all, TPB, 0);
        coop_ok = (e == hipSuccess && nblk_per_cu >= 2) ? 1 : 0;
    }

    if (coop_ok) {
        void* kargs[] = {(void*)&W, (void*)&x, (void*)&b, (void*)&ea,
                         (void*)&y_out, (void*)&W2_out, (void*)&ea_out,
                         (void*)&u_part, (void*)&P};
        hipLaunchCooperativeKernel((const void*)k_all, dim3(NBLK), dim3(TPB),
                                   kargs, 0, stream);
    } else {
        float* u   = u_part;                    // reuse ws: [D]
        float* gfp = u_part + D;                // [D]
        float* gfn = u_part + 2 * D;            // [D]
        k_gemv<<<D / 4, 256, 0, stream>>>(W, x, b, u);
        k_stats<<<1, 1024, 0, stream>>>(u, ea, y_out, ea_out, gfp, gfn);
        dim3 grid(NCT, NCHUNK);
        k_partial<<<grid, TPB, 0, stream>>>(W, y_out, P);
        k_update<<<grid, TPB, 0, stream>>>(W, x, y_out, P, gfp, gfn, W2_out);
    }
}

// Round 5
// 52.068 us; speedup vs baseline: 1.7876x; 1.0568x over previous
//
#include <hip/hip_runtime.h>
#include <math.h>

// Problem constants (D_IN == D_OUT == 4096)
constexpr int   D     = 4096;
constexpr float ALPHA = 0.001f;   // heb_lr
constexpr float GAMMA = 0.99f;
constexpr float EPSC  = 0.0001f;

// Scan decomposition
constexpr int CHUNK  = 32;             // rows per chunk
constexpr int NCHUNK = D / CHUNK;      // 128
constexpr int TPB    = 256;
constexpr int CPB    = TPB * 4;        // 1024 cols per block (float4/thread)
constexpr int NCT    = D / CPB;        // 4 column tiles

using vf4 = float __attribute__((ext_vector_type(4)));

// ---------------------------------------------------------------------------
// Kernel 1: u = W @ x + b   (one wave per row, float4 coalesced)
// ---------------------------------------------------------------------------
__global__ __launch_bounds__(256) void k_gemv(const float* __restrict__ W,
                                              const float* __restrict__ x,
                                              const float* __restrict__ b,
                                              float* __restrict__ u) {
    const int wave = threadIdx.x >> 6;        // 0..3
    const int lane = threadIdx.x & 63;
    const int row  = (blockIdx.x << 2) + wave;
    const float4* Wr = reinterpret_cast<const float4*>(W + (size_t)row * D);
    const float4* xv = reinterpret_cast<const float4*>(x);
    float acc = 0.f;
    #pragma unroll
    for (int it = 0; it < D / 256; ++it) {    // 16 iterations: 64 lanes x float4
        const float4 w  = Wr[lane + it * 64];
        const float4 xx = xv[lane + it * 64];
        acc += w.x * xx.x + w.y * xx.y + w.z * xx.z + w.w * xx.w;
    }
    #pragma unroll
    for (int off = 32; off; off >>= 1) acc += __shfl_down(acc, off, 64);
    if (lane == 0) u[row] = acc + b[row];
}

// ---------------------------------------------------------------------------
// Kernel 2: fused stats + chunk partials.
// Every block redundantly computes m = max(relu(u)) and avg(ea_new) with an
// IDENTICAL reduction order (bitwise-equal across blocks), derives its own
// chunk's y / gf factors in LDS, then computes the chunk column partials
//   P[c,j] = sum_{k in chunk c} y[k] * W[k,j].
// Blocks with t==0 write the y / ea / gf globals for their chunk rows.
// Replaces the single-block latency-bound k_stats + one launch.
// ---------------------------------------------------------------------------
__global__ __launch_bounds__(256) void k_pstats(const float* __restrict__ u,
                                                const float* __restrict__ ea,
                                                const float* __restrict__ W,
                                                float* __restrict__ y_out,
                                                float* __restrict__ ea_out,
                                                float* __restrict__ gfp,
                                                float* __restrict__ gfn,
                                                float* __restrict__ P) {
    const int tid  = threadIdx.x;
    const int t    = blockIdx.x;
    const int c    = blockIdx.y;
    const int j    = t * CPB + tid * 4;
    const int k0   = c * CHUNK;
    const int wv   = tid >> 6;
    const int lane = tid & 63;

    __shared__ float sred[4];
    __shared__ float sm[2];                   // m, sum(ea_new)
    __shared__ float sy[CHUNK], s_unused;     // y for own chunk

    // pass 1: m = max(relu(u))   (relu folded into 0-init of the max)
    float lmax = 0.f;
    #pragma unroll
    for (int i = 0; i < D / TPB; ++i)
        lmax = fmaxf(lmax, u[i * TPB + tid]);
    #pragma unroll
    for (int off = 32; off; off >>= 1) lmax = fmaxf(lmax, __shfl_down(lmax, off, 64));
    if (lane == 0) sred[wv] = lmax;
    __syncthreads();
    if (tid == 0) sm[0] = fmaxf(fmaxf(sred[0], sred[1]), fmaxf(sred[2], sred[3]));
    __syncthreads();
    const float m      = sm[0];
    const float inv_m2 = 1.f / (m * m);

    // pass 2: sum(ea_new) for the mean
    float lsum = 0.f;
    #pragma unroll
    for (int i = 0; i < D / TPB; ++i) {
        const int r  = i * TPB + tid;
        const float rr = fmaxf(u[r], 0.f);
        const float yv = rr * rr * inv_m2;            // r^2 / m^2 (LAMB=2)
        lsum += GAMMA * ea[r] + (1.f - GAMMA) * yv;
    }
    #pragma unroll
    for (int off = 32; off; off >>= 1) lsum += __shfl_down(lsum, off, 64);
    if (lane == 0) sred[wv] = lsum;                   // safe: all passed prior sync
    __syncthreads();
    if (tid == 0) sm[1] = (sred[0] + sred[1]) + (sred[2] + sred[3]);
    __syncthreads();
    const float inv_avg = (float)D / sm[1];

    // own-chunk y / gf; t==0 writes the globals for these 32 rows
    if (tid < CHUNK) {
        const int r = k0 + tid;
        const float rr = fmaxf(u[r], 0.f);
        const float yv = rr * rr * inv_m2;
        const float ev = GAMMA * ea[r] + (1.f - GAMMA) * yv;
        const float a  = ev * inv_avg;
        const float g  = EPSC * tanhf(-EPSC * (a - 1.f)) + 1.f;
        sy[tid] = yv;
        if (t == 0) {
            y_out[r]  = yv;
            ea_out[r] = ev;
            gfp[r]    = g;
            gfn[r]    = 1.f / g;
        }
    }
    __syncthreads();

    // chunk column partials
    const float4* Wp = reinterpret_cast<const float4*>(W + (size_t)k0 * D + j);
    float4 acc = make_float4(0.f, 0.f, 0.f, 0.f);
    #pragma unroll
    for (int k = 0; k < CHUNK; ++k) {
        const float yv = sy[k];
        const float4 w = Wp[(size_t)k * (D / 4)];
        acc.x += yv * w.x; acc.y += yv * w.y;
        acc.z += yv * w.z; acc.w += yv * w.w;
    }
    *reinterpret_cast<float4*>(P + (size_t)c * D + j) = acc;
    (void)s_unused;
}

// ---------------------------------------------------------------------------
// Kernel 3: exclusive prefix over preceding chunk partials (independent,
// coalesced, L2/L3-resident), resume inclusive scan within chunk, fuse
// Hebbian delta + sign-split decay. W2 stored non-temporally (write-once,
// keep W resident in L3 across kernels and graph replays).
// ---------------------------------------------------------------------------
__global__ __launch_bounds__(256) void k_update(const float* __restrict__ W,
                                                const float* __restrict__ x,
                                                const float* __restrict__ y,
                                                const float* __restrict__ P,
                                                const float* __restrict__ gfp,
                                                const float* __restrict__ gfn,
                                                float* __restrict__ W2) {
    const int tid = threadIdx.x;
    const int j   = blockIdx.x * CPB + tid * 4;
    const int c   = blockIdx.y;
    const int k0  = c * CHUNK;

    __shared__ float sy[CHUNK], sgp[CHUNK], sgn[CHUNK];
    if (tid < CHUNK) {
        const int r = k0 + tid;
        sy[tid]  = y[r];
        sgp[tid] = gfp[r];
        sgn[tid] = gfn[r];
    }
    __syncthreads();

    // Exclusive prefix: sum of preceding chunk partials.
    const float4* Pp = reinterpret_cast<const float4*>(P + j);
    float4 a0 = make_float4(0.f, 0.f, 0.f, 0.f);
    float4 a1 = make_float4(0.f, 0.f, 0.f, 0.f);
    int i = 0;
    #pragma unroll 8
    for (; i + 2 <= c; i += 2) {
        const float4 p0 = Pp[(size_t)i * (D / 4)];
        const float4 p1 = Pp[(size_t)(i + 1) * (D / 4)];
        a0.x += p0.x; a0.y += p0.y; a0.z += p0.z; a0.w += p0.w;
        a1.x += p1.x; a1.y += p1.y; a1.z += p1.z; a1.w += p1.w;
    }
    if (i < c) {
        const float4 p0 = Pp[(size_t)i * (D / 4)];
        a0.x += p0.x; a0.y += p0.y; a0.z += p0.z; a0.w += p0.w;
    }
    float4 s;
    s.x = a0.x + a1.x; s.y = a0.y + a1.y;
    s.z = a0.z + a1.z; s.w = a0.w + a1.w;

    const float4 xv = *reinterpret_cast<const float4*>(x + j);
    const float4* Wp  = reinterpret_cast<const float4*>(W + (size_t)k0 * D + j);
    float4*       W2p = reinterpret_cast<float4*>(W2 + (size_t)k0 * D + j);
    #pragma unroll 4
    for (int k = 0; k < CHUNK; ++k) {
        const float yv = sy[k];
        const float gp = sgp[k];
        const float gn = sgn[k];
        const float4 w = Wp[(size_t)k * (D / 4)];
        s.x += yv * w.x; s.y += yv * w.y;
        s.z += yv * w.z; s.w += yv * w.w;
        vf4 o;
        {
            const float w1 = w.x + ALPHA * (yv * xv.x - yv * s.x);
            o.x = w1 > 0.f ? w1 * gp : (w1 < 0.f ? w1 * gn : 0.f);
        }
        {
            const float w1 = w.y + ALPHA * (yv * xv.y - yv * s.y);
            o.y = w1 > 0.f ? w1 * gp : (w1 < 0.f ? w1 * gn : 0.f);
        }
        {
            const float w1 = w.z + ALPHA * (yv * xv.z - yv * s.z);
            o.z = w1 > 0.f ? w1 * gp : (w1 < 0.f ? w1 * gn : 0.f);
        }
        {
            const float w1 = w.w + ALPHA * (yv * xv.w - yv * s.w);
            o.w = w1 > 0.f ? w1 * gp : (w1 < 0.f ? w1 * gn : 0.f);
        }
        __builtin_nontemporal_store(o, reinterpret_cast<vf4*>(W2p + (size_t)k * (D / 4)));
    }
}

// ---------------------------------------------------------------------------
extern "C" void kernel_launch(void* const* d_in, const int* in_sizes, int n_in,
                              void* d_out, int out_size, void* d_ws, size_t ws_size,
                              hipStream_t stream) {
    const float* x  = (const float*)d_in[0];
    const float* W  = (const float*)d_in[1];
    const float* b  = (const float*)d_in[2];
    const float* ea = (const float*)d_in[3];

    float* out    = (float*)d_out;
    float* y_out  = out;                        // [D]
    float* W2_out = out + D;                    // [D*D]
    float* ea_out = out + D + (size_t)D * D;    // [D]

    float* ws  = (float*)d_ws;
    float* u   = ws;                            // [D]
    float* gfp = ws + D;                        // [D]
    float* gfn = ws + 2 * D;                    // [D]
    float* P   = ws + 3 * D;                    // [NCHUNK * D] = 2 MB

    k_gemv<<<D / 4, 256, 0, stream>>>(W, x, b, u);
    dim3 grid(NCT, NCHUNK);
    k_pstats<<<grid, TPB, 0, stream>>>(u, ea, W, y_out, ea_out, gfp, gfn, P);
    k_update<<<grid, TPB, 0, stream>>>(W, x, y_out, P, gfp, gfn, W2_out);
}

// Round 6
// 51.714 us; speedup vs baseline: 1.7998x; 1.0068x over previous
//
#include <hip/hip_runtime.h>
#include <math.h>

// Problem constants (D_IN == D_OUT == 4096)
constexpr int   D     = 4096;
constexpr float ALPHA = 0.001f;   // heb_lr
constexpr float GAMMA = 0.99f;
constexpr float EPSC  = 0.0001f;

// Scan decomposition: 64-row chunks x 512-col tiles -> 512 blocks (2/CU).
// CHUNK=64 (vs 32) cuts exclusive-prefix traffic 4x (130 MB -> 32 MB).
constexpr int CHUNK  = 64;             // rows per chunk
constexpr int NCHUNK = D / CHUNK;      // 64
constexpr int TPB    = 128;
constexpr int CPB    = TPB * 4;        // 512 cols per block (float4/thread)
constexpr int NCT    = D / CPB;        // 8 column tiles

using vf4 = float __attribute__((ext_vector_type(4)));

// ---------------------------------------------------------------------------
// Kernel 1: u = W @ x + b   (one wave per row, float4 coalesced)
// ---------------------------------------------------------------------------
__global__ __launch_bounds__(256) void k_gemv(const float* __restrict__ W,
                                              const float* __restrict__ x,
                                              const float* __restrict__ b,
                                              float* __restrict__ u) {
    const int wave = threadIdx.x >> 6;        // 0..3
    const int lane = threadIdx.x & 63;
    const int row  = (blockIdx.x << 2) + wave;
    const float4* Wr = reinterpret_cast<const float4*>(W + (size_t)row * D);
    const float4* xv = reinterpret_cast<const float4*>(x);
    float acc = 0.f;
    #pragma unroll
    for (int it = 0; it < D / 256; ++it) {    // 16 iterations: 64 lanes x float4
        const float4 w  = Wr[lane + it * 64];
        const float4 xx = xv[lane + it * 64];
        acc += w.x * xx.x + w.y * xx.y + w.z * xx.z + w.w * xx.w;
    }
    #pragma unroll
    for (int off = 32; off; off >>= 1) acc += __shfl_down(acc, off, 64);
    if (lane == 0) u[row] = acc + b[row];
}

// ---------------------------------------------------------------------------
// Kernel 2: fused stats + chunk partials.
// Every block redundantly computes m = max(relu(u)) and avg(ea_new) with an
// IDENTICAL reduction order (bitwise-equal across blocks), derives its own
// chunk's y into LDS, then computes the chunk column partials
//   P[c,j] = sum_{k in chunk c} y[k] * W[k,j].
// Blocks with t==0 write the y / ea / gf globals for their chunk rows.
// ---------------------------------------------------------------------------
__global__ __launch_bounds__(TPB) void k_pstats(const float* __restrict__ u,
                                                const float* __restrict__ ea,
                                                const float* __restrict__ W,
                                                float* __restrict__ y_out,
                                                float* __restrict__ ea_out,
                                                float* __restrict__ gfp,
                                                float* __restrict__ gfn,
                                                float* __restrict__ P) {
    const int tid  = threadIdx.x;
    const int t    = blockIdx.x;
    const int c    = blockIdx.y;
    const int j    = t * CPB + tid * 4;
    const int k0   = c * CHUNK;
    const int wv   = tid >> 6;               // 0..1
    const int lane = tid & 63;

    __shared__ float sred[2];
    __shared__ float sm[2];                   // m, sum(ea_new)
    __shared__ float sy[CHUNK];               // y for own chunk

    // pass 1: m = max(relu(u))   (relu folded into 0-init of the max)
    float lmax = 0.f;
    #pragma unroll
    for (int i = 0; i < D / TPB; ++i)
        lmax = fmaxf(lmax, u[i * TPB + tid]);
    #pragma unroll
    for (int off = 32; off; off >>= 1) lmax = fmaxf(lmax, __shfl_down(lmax, off, 64));
    if (lane == 0) sred[wv] = lmax;
    __syncthreads();
    if (tid == 0) sm[0] = fmaxf(sred[0], sred[1]);
    __syncthreads();
    const float m      = sm[0];
    const float inv_m2 = 1.f / (m * m);

    // pass 2: sum(ea_new) for the mean
    float lsum = 0.f;
    #pragma unroll
    for (int i = 0; i < D / TPB; ++i) {
        const int r  = i * TPB + tid;
        const float rr = fmaxf(u[r], 0.f);
        const float yv = rr * rr * inv_m2;            // r^2 / m^2 (LAMB=2)
        lsum += GAMMA * ea[r] + (1.f - GAMMA) * yv;
    }
    #pragma unroll
    for (int off = 32; off; off >>= 1) lsum += __shfl_down(lsum, off, 64);
    if (lane == 0) sred[wv] = lsum;                   // safe: all passed prior sync
    __syncthreads();
    if (tid == 0) sm[1] = sred[0] + sred[1];
    __syncthreads();
    const float inv_avg = (float)D / sm[1];

    // own-chunk y; t==0 blocks write the y / ea / gf globals for these rows
    if (tid < CHUNK) {
        const int r = k0 + tid;
        const float rr = fmaxf(u[r], 0.f);
        const float yv = rr * rr * inv_m2;
        sy[tid] = yv;
        if (t == 0) {
            const float ev = GAMMA * ea[r] + (1.f - GAMMA) * yv;
            const float a  = ev * inv_avg;
            const float g  = EPSC * tanhf(-EPSC * (a - 1.f)) + 1.f;
            y_out[r]  = yv;
            ea_out[r] = ev;
            gfp[r]    = g;
            gfn[r]    = 1.f / g;
        }
    }
    __syncthreads();

    // chunk column partials
    const float4* Wp = reinterpret_cast<const float4*>(W + (size_t)k0 * D + j);
    float4 acc = make_float4(0.f, 0.f, 0.f, 0.f);
    #pragma unroll 8
    for (int k = 0; k < CHUNK; ++k) {
        const float yv = sy[k];
        const float4 w = Wp[(size_t)k * (D / 4)];
        acc.x += yv * w.x; acc.y += yv * w.y;
        acc.z += yv * w.z; acc.w += yv * w.w;
    }
    *reinterpret_cast<float4*>(P + (size_t)c * D + j) = acc;
}

// ---------------------------------------------------------------------------
// Kernel 3: exclusive prefix over preceding chunk partials (independent,
// coalesced, L2/L3-resident), resume inclusive scan within chunk, fuse
// Hebbian delta + sign-split decay. W2 stored non-temporally (write-once;
// keep W resident in L3).
// ---------------------------------------------------------------------------
__global__ __launch_bounds__(TPB) void k_update(const float* __restrict__ W,
                                                const float* __restrict__ x,
                                                const float* __restrict__ y,
                                                const float* __restrict__ P,
                                                const float* __restrict__ gfp,
                                                const float* __restrict__ gfn,
                                                float* __restrict__ W2) {
    const int tid = threadIdx.x;
    const int j   = blockIdx.x * CPB + tid * 4;
    const int c   = blockIdx.y;
    const int k0  = c * CHUNK;

    __shared__ float sy[CHUNK], sgp[CHUNK], sgn[CHUNK];
    if (tid < CHUNK) {
        const int r = k0 + tid;
        sy[tid]  = y[r];
        sgp[tid] = gfp[r];
        sgn[tid] = gfn[r];
    }
    __syncthreads();

    // Exclusive prefix: sum of preceding chunk partials (c <= 63 rows).
    const float4* Pp = reinterpret_cast<const float4*>(P + j);
    float4 a0 = make_float4(0.f, 0.f, 0.f, 0.f);
    float4 a1 = make_float4(0.f, 0.f, 0.f, 0.f);
    int i = 0;
    #pragma unroll 8
    for (; i + 2 <= c; i += 2) {
        const float4 p0 = Pp[(size_t)i * (D / 4)];
        const float4 p1 = Pp[(size_t)(i + 1) * (D / 4)];
        a0.x += p0.x; a0.y += p0.y; a0.z += p0.z; a0.w += p0.w;
        a1.x += p1.x; a1.y += p1.y; a1.z += p1.z; a1.w += p1.w;
    }
    if (i < c) {
        const float4 p0 = Pp[(size_t)i * (D / 4)];
        a0.x += p0.x; a0.y += p0.y; a0.z += p0.z; a0.w += p0.w;
    }
    float4 s;
    s.x = a0.x + a1.x; s.y = a0.y + a1.y;
    s.z = a0.z + a1.z; s.w = a0.w + a1.w;

    const float4 xv = *reinterpret_cast<const float4*>(x + j);
    const float4* Wp  = reinterpret_cast<const float4*>(W + (size_t)k0 * D + j);
    float4*       W2p = reinterpret_cast<float4*>(W2 + (size_t)k0 * D + j);
    #pragma unroll 4
    for (int k = 0; k < CHUNK; ++k) {
        const float yv = sy[k];
        const float gp = sgp[k];
        const float gn = sgn[k];
        const float4 w = Wp[(size_t)k * (D / 4)];
        s.x += yv * w.x; s.y += yv * w.y;
        s.z += yv * w.z; s.w += yv * w.w;
        vf4 o;
        {
            const float w1 = w.x + ALPHA * (yv * xv.x - yv * s.x);
            o.x = w1 > 0.f ? w1 * gp : (w1 < 0.f ? w1 * gn : 0.f);
        }
        {
            const float w1 = w.y + ALPHA * (yv * xv.y - yv * s.y);
            o.y = w1 > 0.f ? w1 * gp : (w1 < 0.f ? w1 * gn : 0.f);
        }
        {
            const float w1 = w.z + ALPHA * (yv * xv.z - yv * s.z);
            o.z = w1 > 0.f ? w1 * gp : (w1 < 0.f ? w1 * gn : 0.f);
        }
        {
            const float w1 = w.w + ALPHA * (yv * xv.w - yv * s.w);
            o.w = w1 > 0.f ? w1 * gp : (w1 < 0.f ? w1 * gn : 0.f);
        }
        __builtin_nontemporal_store(o, reinterpret_cast<vf4*>(W2p + (size_t)k * (D / 4)));
    }
}

// ---------------------------------------------------------------------------
extern "C" void kernel_launch(void* const* d_in, const int* in_sizes, int n_in,
                              void* d_out, int out_size, void* d_ws, size_t ws_size,
                              hipStream_t stream) {
    const float* x  = (const float*)d_in[0];
    const float* W  = (const float*)d_in[1];
    const float* b  = (const float*)d_in[2];
    const float* ea = (const float*)d_in[3];

    float* out    = (float*)d_out;
    float* y_out  = out;                        // [D]
    float* W2_out = out + D;                    // [D*D]
    float* ea_out = out + D + (size_t)D * D;    // [D]

    float* ws  = (float*)d_ws;
    float* u   = ws;                            // [D]
    float* gfp = ws + D;                        // [D]
    float* gfn = ws + 2 * D;                    // [D]
    float* P   = ws + 3 * D;                    // [NCHUNK * D] = 1 MB

    k_gemv<<<D / 4, 256, 0, stream>>>(W, x, b, u);
    dim3 grid(NCT, NCHUNK);
    k_pstats<<<grid, TPB, 0, stream>>>(u, ea, W, y_out, ea_out, gfp, gfn, P);
    k_update<<<grid, TPB, 0, stream>>>(W, x, y_out, P, gfp, gfn, W2_out);
}